// Round 1
// baseline (99.428 us; speedup 1.0000x reference)
//
#include <hip/hip_runtime.h>

#define SS 17
#define AA 5
#define CC 20
#define BATCH 256
#define GG 32
#define HWC (SS * SS)        // 289
#define NP (HWC * AA)        // 1445
#define SPLIT 4
#define NTHREADS 256

__global__ __launch_bounds__(NTHREADS) void yolo_loss_kernel(
    const float* __restrict__ bbox,    // (B, HW, A, 4)
    const float* __restrict__ ioup,    // (B, HW, A, 1)
    const float* __restrict__ score,   // (B, HW, A, C)
    const float* __restrict__ tgt,     // (B*G, 6)
    const float* __restrict__ anchors, // (A, 2)
    float* __restrict__ out)
{
    const int b   = blockIdx.x;
    const int spl = blockIdx.y;
    const int tid = threadIdx.x;

    __shared__ float gx1[GG], gy1[GG], gx2[GG], gy2[GG], garea[GG];
    __shared__ float tarb[GG][4];
    __shared__ int   gcls[GG];
    __shared__ float anc[AA][2];
    __shared__ short assign[NP + 1];
    __shared__ float wsum[NTHREADS / 64];

    // Phase A: init assignment table + load normalized anchors
    for (int p = tid; p < NP; p += NTHREADS) assign[p] = -1;
    if (tid < AA * 2) ((float*)anc)[tid] = anchors[tid] * (1.0f / 17.0f);
    __syncthreads();

    // Phase B: per-GT preprocessing (32 threads)
    if (tid < GG) {
        const float* t = tgt + (size_t)(b * GG + tid) * 6;
        int   cls = (int)t[1];
        float x1 = t[2], y1 = t[3], x2 = t[4], y2 = t[5];
        float cx = (x1 + x2) * 0.5f, cy = (y1 + y2) * 0.5f;
        float gw = x2 - x1, gh = y2 - y1;
        float cxs = cx * (float)SS, cys = cy * (float)SS;
        int ci = (int)floorf(cxs), cj = (int)floorf(cys);
        gx1[tid] = x1; gy1[tid] = y1; gx2[tid] = x2; gy2[tid] = y2;
        garea[tid] = gw * gh;
        tarb[tid][0] = cxs - (float)ci;
        tarb[tid][1] = cys - (float)cj;
        tarb[tid][2] = gw;
        tarb[tid][3] = gh;
        gcls[tid] = cls;
        // anchor argmax (first max wins, matching jnp.argmax)
        float best = -1.0f; int bi = 0;
        for (int a = 0; a < AA; a++) {
            float aw = anc[a][0], ah = anc[a][1];
            float inter = fminf(aw, gw) * fminf(ah, gh);
            float u = aw * ah + gw * gh - inter;
            float v = inter / u;
            if (v > best) { best = v; bi = a; }
        }
        int cell = ci * SS + cj;
        assign[cell * AA + bi] = (short)tid;
    }
    __syncthreads();

    // Phase C: main loop over pred boxes
    float acc = 0.0f;
    const int base = b * NP;
    for (int p = spl * NTHREADS + tid; p < NP; p += NTHREADS * SPLIT) {
        float4 bb = ((const float4*)bbox)[base + p];
        float  ip = ioup[base + p];
        int hw = p / AA;
        int a  = p - hw * AA;
        int i  = hw / SS;
        int j  = hw - i * SS;

        float px = (bb.x + (float)i) * (1.0f / SS);
        float py = (bb.y + (float)j) * (1.0f / SS);
        float pw = bb.z * anc[a][0] * (1.0f / SS);
        float ph = bb.w * anc[a][1] * (1.0f / SS);
        float px1 = px - pw * 0.5f, py1 = py - ph * 0.5f;
        float px2 = px + pw * 0.5f, py2 = py + ph * 0.5f;
        float parea = (px2 - px1) * (py2 - py1);

        int ga = (int)assign[p];
        float best = 0.0f;   // IoU >= 0 always
        float iou_t = 0.0f;
        #pragma unroll 8
        for (int g = 0; g < GG; g++) {
            float lx = fmaxf(px1, gx1[g]);
            float ly = fmaxf(py1, gy1[g]);
            float rx = fminf(px2, gx2[g]);
            float ry = fminf(py2, gy2[g]);
            float w  = fmaxf(rx - lx, 0.0f);
            float h  = fmaxf(ry - ly, 0.0f);
            float inter = w * h;
            float iou = inter / (parea + garea[g] - inter);
            best = fmaxf(best, iou);
            if (g == ga) iou_t = iou;
        }

        if (ga >= 0) {
            // box loss (mask = 1)
            float dx = bb.x - tarb[ga][0];
            float dy = bb.y - tarb[ga][1];
            float dw = bb.z - tarb[ga][2];
            float dh = bb.w - tarb[ga][3];
            acc += dx * dx + dy * dy + dw * dw + dh * dh;
            // iou loss: mask = OBJ_SCALE*(1-ip), target = iou_t
            float m = 5.0f * (1.0f - ip);
            float d = ip - iou_t;
            acc += (m * m) * (d * d);
            // class loss: mask = 1 on this row only
            const float* sp = score + (size_t)(base + p) * CC;
            int cls = gcls[ga];
            float csum = 0.0f;
            #pragma unroll
            for (int c = 0; c < CC; c++) {
                float v = sp[c] - (c == cls ? 1.0f : 0.0f);
                csum += v * v;
            }
            acc += csum;
        } else {
            // box loss (mask = 0.01 -> 1e-4 factor), target = (0.5,0.5,1,1)
            float dx = bb.x - 0.5f, dy = bb.y - 0.5f;
            float dw = bb.z - 1.0f, dh = bb.w - 1.0f;
            acc += 1e-4f * (dx * dx + dy * dy + dw * dw + dh * dh);
            // noobj iou loss: mask = -ip, target 0 -> ip^4 (only if best<=0.6)
            if (best <= 0.6f) {
                float q = ip * ip;
                acc += q * q;
            }
        }
    }

    // Phase D: reduction (wave64 shuffle, then LDS across 4 waves)
    #pragma unroll
    for (int off = 32; off > 0; off >>= 1)
        acc += __shfl_down(acc, off, 64);
    if ((tid & 63) == 0) wsum[tid >> 6] = acc;
    __syncthreads();
    if (tid == 0) {
        float s = 0.0f;
        #pragma unroll
        for (int w = 0; w < NTHREADS / 64; w++) s += wsum[w];
        atomicAdd(out, s * (1.0f / (float)GG));
    }
}

extern "C" void kernel_launch(void* const* d_in, const int* in_sizes, int n_in,
                              void* d_out, int out_size, void* d_ws, size_t ws_size,
                              hipStream_t stream) {
    const float* bbox    = (const float*)d_in[0];
    const float* ioup    = (const float*)d_in[1];
    const float* score   = (const float*)d_in[2];
    const float* tgt     = (const float*)d_in[3];
    const float* anchors = (const float*)d_in[4];
    float* out = (float*)d_out;

    hipMemsetAsync(out, 0, sizeof(float), stream);
    dim3 grid(BATCH, SPLIT);
    yolo_loss_kernel<<<grid, NTHREADS, 0, stream>>>(bbox, ioup, score, tgt, anchors, out);
}

// Round 2
// 91.944 us; speedup vs baseline: 1.0814x; 1.0814x over previous
//
#include <hip/hip_runtime.h>

#define SS 17
#define AA 5
#define CC 20
#define BATCH 256
#define GG 32
#define HWC (SS * SS)        // 289
#define NP (HWC * AA)        // 1445
#define SPLIT 4
#define NTHREADS 256
#define NPART (BATCH * SPLIT)

__global__ __launch_bounds__(NTHREADS) void yolo_loss_kernel(
    const float* __restrict__ bbox,    // (B, HW, A, 4)
    const float* __restrict__ ioup,    // (B, HW, A, 1)
    const float* __restrict__ score,   // (B, HW, A, C)
    const float* __restrict__ tgt,     // (B*G, 6)
    const float* __restrict__ anchors, // (A, 2)
    float* __restrict__ part)          // (B*SPLIT,) partial sums
{
    const int b   = blockIdx.x;
    const int spl = blockIdx.y;
    const int tid = threadIdx.x;

    __shared__ float gx1[GG], gy1[GG], gx2[GG], gy2[GG], garea[GG];
    __shared__ float tarb[GG][4];
    __shared__ int   gcls[GG];
    __shared__ float anc[AA][2];
    __shared__ short assign[NP + 1];
    __shared__ float wsum[NTHREADS / 64];

    // Phase A: init assignment table + load normalized anchors
    for (int p = tid; p < NP; p += NTHREADS) assign[p] = -1;
    if (tid < AA * 2) ((float*)anc)[tid] = anchors[tid] * (1.0f / 17.0f);
    __syncthreads();

    // Phase B: per-GT preprocessing (32 threads). Cells are distinct per
    // image by construction, so no (cell,anchor) write collisions.
    if (tid < GG) {
        const float* t = tgt + (size_t)(b * GG + tid) * 6;
        int   cls = (int)t[1];
        float x1 = t[2], y1 = t[3], x2 = t[4], y2 = t[5];
        float cx = (x1 + x2) * 0.5f, cy = (y1 + y2) * 0.5f;
        float gw = x2 - x1, gh = y2 - y1;
        float cxs = cx * (float)SS, cys = cy * (float)SS;
        int ci = (int)floorf(cxs), cj = (int)floorf(cys);
        gx1[tid] = x1; gy1[tid] = y1; gx2[tid] = x2; gy2[tid] = y2;
        garea[tid] = gw * gh;
        tarb[tid][0] = cxs - (float)ci;
        tarb[tid][1] = cys - (float)cj;
        tarb[tid][2] = gw;
        tarb[tid][3] = gh;
        gcls[tid] = cls;
        // anchor argmax (first max wins, matching jnp.argmax)
        float best = -1.0f; int bi = 0;
        for (int a = 0; a < AA; a++) {
            float aw = anc[a][0], ah = anc[a][1];
            float inter = fminf(aw, gw) * fminf(ah, gh);
            float u = aw * ah + gw * gh - inter;
            float v = inter / u;
            if (v > best) { best = v; bi = a; }
        }
        int cell = ci * SS + cj;
        assign[cell * AA + bi] = (short)tid;
    }
    __syncthreads();

    // Phase C: main loop over pred boxes
    float acc = 0.0f;
    const int base = b * NP;
    for (int p = spl * NTHREADS + tid; p < NP; p += NTHREADS * SPLIT) {
        float4 bb = ((const float4*)bbox)[base + p];
        float  ip = ioup[base + p];
        int hw = p / AA;
        int a  = p - hw * AA;
        int i  = hw / SS;
        int j  = hw - i * SS;

        float px = (bb.x + (float)i) * (1.0f / SS);
        float py = (bb.y + (float)j) * (1.0f / SS);
        float pw = bb.z * anc[a][0] * (1.0f / SS);
        float ph = bb.w * anc[a][1] * (1.0f / SS);
        float px1 = px - pw * 0.5f, py1 = py - ph * 0.5f;
        float px2 = px + pw * 0.5f, py2 = py + ph * 0.5f;
        float parea = (px2 - px1) * (py2 - py1);

        int ga = (int)assign[p];
        float best = 0.0f;   // IoU >= 0 always
        float iou_t = 0.0f;
        #pragma unroll 8
        for (int g = 0; g < GG; g++) {
            float lx = fmaxf(px1, gx1[g]);
            float ly = fmaxf(py1, gy1[g]);
            float rx = fminf(px2, gx2[g]);
            float ry = fminf(py2, gy2[g]);
            float w  = fmaxf(rx - lx, 0.0f);
            float h  = fmaxf(ry - ly, 0.0f);
            float inter = w * h;
            float iou = inter / (parea + garea[g] - inter);
            best = fmaxf(best, iou);
            if (g == ga) iou_t = iou;
        }

        if (ga >= 0) {
            // box loss (mask = 1)
            float dx = bb.x - tarb[ga][0];
            float dy = bb.y - tarb[ga][1];
            float dw = bb.z - tarb[ga][2];
            float dh = bb.w - tarb[ga][3];
            acc += dx * dx + dy * dy + dw * dw + dh * dh;
            // iou loss: mask = OBJ_SCALE*(1-ip), target = iou_t
            float m = 5.0f * (1.0f - ip);
            float d = ip - iou_t;
            acc += (m * m) * (d * d);
            // class loss: mask = 1 on this row only; row is 80B = 16B-aligned
            const float4* sp4 = (const float4*)(score + (size_t)(base + p) * CC);
            int cls = gcls[ga];
            float csum = 0.0f;
            #pragma unroll
            for (int c4 = 0; c4 < CC / 4; c4++) {
                float4 sv = sp4[c4];
                float v0 = sv.x - (4 * c4 + 0 == cls ? 1.0f : 0.0f);
                float v1 = sv.y - (4 * c4 + 1 == cls ? 1.0f : 0.0f);
                float v2 = sv.z - (4 * c4 + 2 == cls ? 1.0f : 0.0f);
                float v3 = sv.w - (4 * c4 + 3 == cls ? 1.0f : 0.0f);
                csum += v0 * v0 + v1 * v1 + v2 * v2 + v3 * v3;
            }
            acc += csum;
        } else {
            // box loss (mask = 0.01 -> 1e-4 factor), target = (0.5,0.5,1,1)
            float dx = bb.x - 0.5f, dy = bb.y - 0.5f;
            float dw = bb.z - 1.0f, dh = bb.w - 1.0f;
            acc += 1e-4f * (dx * dx + dy * dy + dw * dw + dh * dh);
            // noobj iou loss: mask = -ip, target 0 -> ip^4 (only if best<=0.6)
            if (best <= 0.6f) {
                float q = ip * ip;
                acc += q * q;
            }
        }
    }

    // Phase D: reduction (wave64 shuffle, then LDS across 4 waves)
    #pragma unroll
    for (int off = 32; off > 0; off >>= 1)
        acc += __shfl_down(acc, off, 64);
    if ((tid & 63) == 0) wsum[tid >> 6] = acc;
    __syncthreads();
    if (tid == 0) {
        float s = 0.0f;
        #pragma unroll
        for (int w = 0; w < NTHREADS / 64; w++) s += wsum[w];
        part[b * SPLIT + spl] = s;   // plain store; every slot written
    }
}

__global__ __launch_bounds__(NTHREADS) void yolo_reduce_kernel(
    const float* __restrict__ part, float* __restrict__ out)
{
    const int tid = threadIdx.x;
    __shared__ float wsum[NTHREADS / 64];
    float s = 0.0f;
    #pragma unroll
    for (int k = 0; k < NPART / NTHREADS; k++)
        s += part[k * NTHREADS + tid];
    #pragma unroll
    for (int off = 32; off > 0; off >>= 1)
        s += __shfl_down(s, off, 64);
    if ((tid & 63) == 0) wsum[tid >> 6] = s;
    __syncthreads();
    if (tid == 0) {
        float t = 0.0f;
        #pragma unroll
        for (int w = 0; w < NTHREADS / 64; w++) t += wsum[w];
        out[0] = t * (1.0f / (float)GG);
    }
}

extern "C" void kernel_launch(void* const* d_in, const int* in_sizes, int n_in,
                              void* d_out, int out_size, void* d_ws, size_t ws_size,
                              hipStream_t stream) {
    const float* bbox    = (const float*)d_in[0];
    const float* ioup    = (const float*)d_in[1];
    const float* score   = (const float*)d_in[2];
    const float* tgt     = (const float*)d_in[3];
    const float* anchors = (const float*)d_in[4];
    float* out  = (float*)d_out;
    float* part = (float*)d_ws;   // 1024 floats of scratch; fully overwritten

    dim3 grid(BATCH, SPLIT);
    yolo_loss_kernel<<<grid, NTHREADS, 0, stream>>>(bbox, ioup, score, tgt, anchors, part);
    yolo_reduce_kernel<<<1, NTHREADS, 0, stream>>>(part, out);
}